// Round 21
// baseline (51.660 us; speedup 1.0000x reference)
//
#include <hip/hip_runtime.h>
#include <hip/hip_bf16.h>
#include <math.h>

typedef int   i32x4 __attribute__((ext_vector_type(4)));
typedef float f32x4 __attribute__((ext_vector_type(4)));

static __device__ __forceinline__ int pack4i8(float4 u) {
    int x0 = (int)rintf(fminf(fmaxf(u.x * 16.0f, -127.0f), 127.0f));
    int x1 = (int)rintf(fminf(fmaxf(u.y * 16.0f, -127.0f), 127.0f));
    int x2 = (int)rintf(fminf(fmaxf(u.z * 16.0f, -127.0f), 127.0f));
    int x3 = (int)rintf(fminf(fmaxf(u.w * 16.0f, -127.0f), 127.0f));
    return (x0 & 255) | ((x1 & 255) << 8) | ((x2 & 255) << 16) | ((x3 & 255) << 24);
}

static __device__ __forceinline__ void async_cp16(const void* gsrc, void* ldsdst) {
    __builtin_amdgcn_global_load_lds(
        (const __attribute__((address_space(1))) void*)gsrc,
        (__attribute__((address_space(3))) void*)ldsdst, 16, 0, 0);
}

// ---- cent_prep_i8 (R20-validated): i8 image + exact fp32 c2; last: zero -----
// img[cb16][kb(0..3)][lane][j] = q16(cent[cb*16 + (lane&15)][kb*64 + (lane>>4)*16 + j])
__global__ __launch_bounds__(256) void cent_prep_kernel(
    const float* __restrict__ cent, char* __restrict__ Cimg,
    float* __restrict__ c2g, float* __restrict__ out, int out_size,
    int ncb, int nblk) {
    const int tid = threadIdx.x, lane = tid & 63, wv = tid >> 6;
    if ((int)blockIdx.x < nblk) {
        const int cb = blockIdx.x * 4 + wv;
        if (cb < ncb) {
            const int r = cb * 16 + (lane & 15);
            const int q = lane >> 4;
            const float4* C4 = (const float4*)cent;
            float s = 0.0f;
            #pragma unroll
            for (int kb = 0; kb < 4; ++kb) {
                i32x4 frag;
                #pragma unroll
                for (int j = 0; j < 4; ++j) {
                    float4 u = C4[(size_t)r * 64 + kb * 16 + q * 4 + j];
                    frag[j] = pack4i8(u);
                    s += u.x*u.x + u.y*u.y + u.z*u.z + u.w*u.w;
                }
                *(i32x4*)(Cimg + ((size_t)(cb * 4 + kb) * 64 + lane) * 16) = frag;
            }
            s += __shfl_xor(s, 16, 64);
            s += __shfl_xor(s, 32, 64);
            if (lane < 16) c2g[cb * 16 + lane] = s;
        }
    } else {
        for (int i = tid; i < out_size; i += 256) out[i] = 0.0f;
    }
}

// ---- main16: R20's int8 winner + 2-way column split = 2 blocks/CU. ----------
// R20 left half the CU idle: 256 blocks x 69.7KB LDS = 1 block/CU. Split the
// column range 2-way -> 512 blocks = 2 blocks/CU (139KB LDS, VGPR ~150 allows
// 3 waves/SIMD): one block's prologue/epilogue/barrier stalls overlap the
// other's compute (R14 evidence: occupancy was the only knob that moved 36%).
// Everything else verbatim R20 (absmax 0.0): q16 int8 MFMA K=64, exact fp32
// e2/c2, d2 = e2+c2-acc/128, pos = label-column select, screen d2<2,
// depth-2 counted vmcnt fills, (256,1).
#define CHUNK_BYTES 16384
// LDS: buf[4] @0 (64KB), c2l @65536 (2KB half-K), det @69632 (16B), red @69648
#define MAIN_SMEM 69664

__global__ __launch_bounds__(256, 1) void main16_kernel(
    const float* __restrict__ emb, const char* __restrict__ Cimg,
    const float* __restrict__ c2g, const int* __restrict__ labw, int lab_nelem,
    float* __restrict__ out, int K, int nchunk, float invB) {
    extern __shared__ char smem[];
    float*    c2l = (float*)(smem + 65536);
    unsigned* det = (unsigned*)(smem + 69632);
    float*    red = (float*)(smem + 69648);

    const int tid = threadIdx.x, lane = tid & 63, wid = tid >> 6;
    const int wr = wid >> 1;          // row half: 64 rows
    const int wc = wid & 1;           // col half: 32 of the 64 chunk cols
    const int nrb = gridDim.x >> 1;   // row blocks
    const int brow0 = ((int)blockIdx.x % nrb) * 128;
    const int chalf = (int)blockIdx.x / nrb;       // column half
    const int cbase = chalf * nchunk;              // first chunk (global idx)
    const int l15 = lane & 15, q = lane >> 4;

#define ISSUE_FILLS(t_) do {                                                  \
        const char* s_ = Cimg + (size_t)(cbase + (t_)) * CHUNK_BYTES;         \
        char* d_ = smem + (size_t)((t_) & 3) * CHUNK_BYTES;                   \
        _Pragma("unroll")                                                     \
        for (int i_ = 0; i_ < 4; ++i_)                                        \
            async_cp16(s_ + (i_ * 256 + tid) * 16, d_ + (i_ * 256 + tid) * 16); \
    } while (0)

    // fills for chunks 0 and 1 FIRST (oldest vmem ops; in-order vmcnt retire)
    ISSUE_FILLS(0);
    ISSUE_FILLS(1);
    asm volatile("" ::: "memory");

    // A: this wave's 64 rows -> i8 fragments (a[m][kb], 64 VGPR); exact e2.
    i32x4 a[4][4];
    float e2m[4];
    #pragma unroll
    for (int m = 0; m < 4; ++m) {
        const int rg = brow0 + wr * 64 + m * 16 + l15;
        const float4* E4 = (const float4*)emb + (size_t)rg * 64;
        float s = 0.0f;
        #pragma unroll
        for (int kb = 0; kb < 4; ++kb) {
            i32x4 frag;
            #pragma unroll
            for (int j = 0; j < 4; ++j) {
                float4 u = E4[kb * 16 + q * 4 + j];
                frag[j] = pack4i8(u);
                s += u.x*u.x + u.y*u.y + u.z*u.z + u.w*u.w;
            }
            a[m][kb] = frag;
        }
        s += __shfl_xor(s, 16, 64);
        s += __shfl_xor(s, 32, 64);
        e2m[m] = s;                    // exact e2 of row wr*64 + m*16 + l15
    }

    // c2 (this column half) -> LDS
    {
        const int kh = nchunk * 64;                // columns in this half
        for (int i = tid; i < kh; i += 256) c2l[i] = c2g[cbase * 64 + i];
    }

    // label-width detect from a small fixed window (identical in all blocks)
    {
        int npairs = lab_nelem / 2; if (npairs > 512) npairs = 512;
        unsigned accw = 0;
        const unsigned* w = (const unsigned*)labw;
        for (int i = tid; i < npairs; i += 256) accw |= w[2 * i + 1];
        #pragma unroll
        for (int d = 32; d >= 1; d >>= 1) accw |= __shfl_xor(accw, d, 64);
        if (lane == 0) det[wid] = accw;
    }
    __syncthreads();
    const int is32 = ((det[0] | det[1] | det[2] | det[3]) != 0);
    const int lab_self = is32 ? labw[brow0 + wr * 64 + lane]
                              : labw[2 * (brow0 + wr * 64 + lane)];

    // acc-row r of tile m is global row wr*64 + m*16 + q*4 + r
    float er[4][4]; int lb[4][4];
    #pragma unroll
    for (int m = 0; m < 4; ++m)
        #pragma unroll
        for (int r = 0; r < 4; ++r) {
            er[m][r] = __shfl(e2m[m], q * 4 + r, 64);
            lb[m][r] = __shfl(lab_self, m * 16 + q * 4 + r, 64);
        }

    float fsum = 0.0f;

#define CHUNK_BODY(t_)  do {                                                  \
        const char* Bbuf = smem + (size_t)((t_) & 3) * CHUNK_BYTES;           \
        const int cl0 = (t_) * 64 + wc * 32 + l15;        /* local col */     \
        const int cg0 = cbase * 64 + cl0;                 /* global col */    \
        const float c2v0 = c2l[cl0];                                          \
        const float c2v1 = c2l[cl0 + 16];                                     \
        i32x4 acc[4][2];                                                      \
        _Pragma("unroll")                                                     \
        for (int m = 0; m < 4; ++m) {                                         \
            acc[m][0] = (i32x4){0, 0, 0, 0};                                  \
            acc[m][1] = (i32x4){0, 0, 0, 0};                                  \
        }                                                                     \
        _Pragma("unroll")                                                     \
        for (int kb = 0; kb < 4; ++kb) {                                      \
            i32x4 b0 = *(const i32x4*)(Bbuf + ((size_t)((wc * 2 + 0) * 4 + kb) * 64 + lane) * 16); \
            i32x4 b1 = *(const i32x4*)(Bbuf + ((size_t)((wc * 2 + 1) * 4 + kb) * 64 + lane) * 16); \
            _Pragma("unroll")                                                 \
            for (int m = 0; m < 4; ++m) {                                     \
                acc[m][0] = __builtin_amdgcn_mfma_i32_16x16x64_i8(a[m][kb], b0, acc[m][0], 0, 0, 0); \
                acc[m][1] = __builtin_amdgcn_mfma_i32_16x16x64_i8(a[m][kb], b1, acc[m][1], 0, 0, 0); \
            }                                                                 \
        }                                                                     \
        float mn = 3.0e38f;                                                   \
        _Pragma("unroll")                                                     \
        for (int m = 0; m < 4; ++m)                                           \
            _Pragma("unroll")                                                 \
            for (int r = 0; r < 4; ++r) {                                     \
                float d20 = fmaf(-0.0078125f, (float)acc[m][0][r], er[m][r] + c2v0); \
                float d21 = fmaf(-0.0078125f, (float)acc[m][1][r], er[m][r] + c2v1); \
                fsum += (cg0 == lb[m][r]) ? fmaxf(d20, 0.0f) : 0.0f;          \
                fsum += (cg0 + 16 == lb[m][r]) ? fmaxf(d21, 0.0f) : 0.0f;     \
                mn = fminf(mn, fminf(d20, d21));                              \
            }                                                                 \
        if (__builtin_expect(__any(mn < 2.0f), 0)) {   /* rare: margin */     \
            _Pragma("unroll")                                                 \
            for (int m = 0; m < 4; ++m)                                       \
                _Pragma("unroll")                                             \
                for (int n = 0; n < 2; ++n)                                   \
                    _Pragma("unroll")                                         \
                    for (int r = 0; r < 4; ++r) {                             \
                        float c2v = (n == 0) ? c2v0 : c2v1;                   \
                        float d2 = fmaxf(fmaf(-0.0078125f, (float)acc[m][n][r], er[m][r] + c2v), 0.0f); \
                        int cg = cg0 + n * 16;                                \
                        if (d2 < 1.0f && cg != lb[m][r]) {                    \
                            float tt = 1.0f - sqrtf(d2);                      \
                            fsum += tt * tt;                                  \
                        }                                                     \
                    }                                                         \
        }                                                                     \
    } while (0)

    // steady loop: fills(t+2) in flight, wait only for fills(t)
    int t = 0;
    for (; t < nchunk - 2; ++t) {
        __builtin_amdgcn_s_barrier();
        ISSUE_FILLS(t + 2);
        asm volatile("s_waitcnt vmcnt(8)" ::: "memory");
        CHUNK_BODY(t);
    }
    __builtin_amdgcn_s_barrier();
    asm volatile("s_waitcnt vmcnt(4)" ::: "memory");
    CHUNK_BODY(t);
    ++t;
    __builtin_amdgcn_s_barrier();
    asm volatile("s_waitcnt vmcnt(0)" ::: "memory");
    CHUNK_BODY(t);

#undef CHUNK_BODY
#undef ISSUE_FILLS

    #pragma unroll
    for (int d = 32; d >= 1; d >>= 1) fsum += __shfl_xor(fsum, d, 64);
    __syncthreads();
    if (lane == 0) red[wid] = fsum;
    __syncthreads();
    if (tid == 0)
        atomicAdd(out, (red[0] + red[1] + red[2] + red[3]) * invB);
}

// ======================= fallback (round-1, verified) ========================
#define FB_THREADS 512
#define FB_SMEM 132672
typedef short bf16x8 __attribute__((ext_vector_type(8)));
__device__ int g_lab_is64;

static __device__ __forceinline__ unsigned short f2bf(float x) {
    unsigned u = __builtin_bit_cast(unsigned, x);
    return (unsigned short)((u + 0x7fffu + ((u >> 16) & 1u)) >> 16);
}

__global__ void fb_detect_kernel(const unsigned* __restrict__ w, int nelem,
                                 float* __restrict__ out, int out_size) {
    __shared__ unsigned red[256];
    unsigned acc = 0;
    for (int i = threadIdx.x; i < nelem / 2; i += 256) acc |= w[2 * i + 1];
    red[threadIdx.x] = acc;
    __syncthreads();
    for (int s = 128; s > 0; s >>= 1) {
        if (threadIdx.x < s) red[threadIdx.x] |= red[threadIdx.x + s];
        __syncthreads();
    }
    if (threadIdx.x == 0) g_lab_is64 = (red[0] == 0u) ? 1 : 0;
    for (int i = threadIdx.x; i < out_size; i += 256) out[i] = 0.0f;
}

__global__ __launch_bounds__(FB_THREADS) void fb_loss_kernel(
    const float* __restrict__ emb, const float* __restrict__ cent,
    const int* __restrict__ labw, float* __restrict__ out,
    int nchunk, float invB) {
    extern __shared__ char smem[];
    char* Abf = smem;
    char* Cbf = smem + 65536;
    float* e2 = (float*)(smem + 131072);
    float* c2 = (float*)(smem + 131584);
    int* lab = (int*)(smem + 132096);
    float* red = (float*)(smem + 132608);

    const int tid = threadIdx.x, lane = tid & 63, wid = tid >> 6;
    const int row0 = blockIdx.x * 128;
    const int is64 = g_lab_is64;

    for (int j = 0; j < 16; ++j) {
        int f4 = tid + j * FB_THREADS;
        int r = f4 >> 6, c4 = f4 & 63;
        float4 v = ((const float4*)emb)[(size_t)(row0 + r) * 64 + c4];
        ushort4 h;
        h.x = f2bf(v.x); h.y = f2bf(v.y); h.z = f2bf(v.z); h.w = f2bf(v.w);
        int off = (c4 * 8) ^ ((r & 7) << 4);
        *(ushort4*)(Abf + r * 512 + off) = h;
        float s = v.x*v.x + v.y*v.y + v.z*v.z + v.w*v.w;
        #pragma unroll
        for (int m = 32; m >= 1; m >>= 1) s += __shfl_xor(s, m, 64);
        if (lane == 0) e2[r] = s;
    }
    if (tid < 128) {
        int b = row0 + tid;
        lab[tid] = is64 ? labw[2 * b] : labw[b];
    }
    __syncthreads();

    const int wr = wid >> 1, wc = wid & 1;
    const int l15 = lane & 15, l16 = lane >> 4;
    const int swz = (l15 & 7) << 4;

    float e2v[2][4]; int labv[2][4];
    #pragma unroll
    for (int m = 0; m < 2; ++m)
        #pragma unroll
        for (int r = 0; r < 4; ++r) {
            int rr = wr * 32 + m * 16 + l16 * 4 + r;
            e2v[m][r] = e2[rr]; labv[m][r] = lab[rr];
        }

    float fsum = 0.0f;
    for (int ch = 0; ch < nchunk; ++ch) {
        const float* cbase = cent + (size_t)ch * 128 * 256;
        for (int j = 0; j < 16; ++j) {
            int f4 = tid + j * FB_THREADS;
            int r = f4 >> 6, c4 = f4 & 63;
            float4 v = ((const float4*)cbase)[(size_t)r * 64 + c4];
            ushort4 h;
            h.x = f2bf(v.x); h.y = f2bf(v.y); h.z = f2bf(v.z); h.w = f2bf(v.w);
            int off = (c4 * 8) ^ ((r & 7) << 4);
            *(ushort4*)(Cbf + r * 512 + off) = h;
            float s = v.x*v.x + v.y*v.y + v.z*v.z + v.w*v.w;
            #pragma unroll
            for (int m = 32; m >= 1; m >>= 1) s += __shfl_xor(s, m, 64);
            if (lane == 0) c2[r] = s;
        }
        __syncthreads();

        f32x4 acc[2][4];
        #pragma unroll
        for (int m = 0; m < 2; ++m)
            #pragma unroll
            for (int n = 0; n < 4; ++n) acc[m][n] = (f32x4){0, 0, 0, 0};

        #pragma unroll
        for (int kk = 0; kk < 8; ++kk) {
            int kb = kk * 64 + l16 * 16;
            bf16x8 a[2], b[4];
            #pragma unroll
            for (int m = 0; m < 2; ++m)
                a[m] = *(const bf16x8*)(Abf + (wr * 32 + m * 16 + l15) * 512 + (kb ^ swz));
            #pragma unroll
            for (int n = 0; n < 4; ++n)
                b[n] = *(const bf16x8*)(Cbf + (wc * 64 + n * 16 + l15) * 512 + (kb ^ swz));
            #pragma unroll
            for (int m = 0; m < 2; ++m)
                #pragma unroll
                for (int n = 0; n < 4; ++n)
                    acc[m][n] = __builtin_amdgcn_mfma_f32_16x16x32_bf16(a[m], b[n], acc[m][n], 0, 0, 0);
        }

        float c2v[4]; int colg[4];
        #pragma unroll
        for (int n = 0; n < 4; ++n) {
            int cl = wc * 64 + n * 16 + l15;
            c2v[n] = c2[cl]; colg[n] = ch * 128 + cl;
        }
        unsigned need = 0;
        #pragma unroll
        for (int m = 0; m < 2; ++m)
            #pragma unroll
            for (int n = 0; n < 4; ++n)
                #pragma unroll
                for (int r = 0; r < 4; ++r) {
                    float d2 = fmaf(-2.0f, acc[m][n][r], e2v[m][r] + c2v[n]);
                    d2 = fmaxf(d2, 0.0f);
                    bool isp = (colg[n] == labv[m][r]);
                    fsum += isp ? d2 : 0.0f;
                    need |= (unsigned)((!isp) & (d2 < 1.0f)) << (m * 16 + n * 4 + r);
                }
        if (__any(need != 0)) {
            #pragma unroll
            for (int m = 0; m < 2; ++m)
                #pragma unroll
                for (int n = 0; n < 4; ++n)
                    #pragma unroll
                    for (int r = 0; r < 4; ++r)
                        if ((need >> (m * 16 + n * 4 + r)) & 1u) {
                            float d2 = fmaf(-2.0f, acc[m][n][r], e2v[m][r] + c2v[n]);
                            d2 = fmaxf(d2, 0.0f);
                            float t = 1.0f - sqrtf(d2);
                            fsum += t * t;
                        }
        }
        __syncthreads();
    }
    #pragma unroll
    for (int m = 32; m >= 1; m >>= 1) fsum += __shfl_xor(fsum, m, 64);
    if (lane == 0) red[wid] = fsum;
    __syncthreads();
    if (tid == 0) {
        float t = 0.0f;
        #pragma unroll
        for (int w = 0; w < 8; ++w) t += red[w];
        atomicAdd(out, t * invB);
    }
}

// =============================================================================
extern "C" void kernel_launch(void* const* d_in, const int* in_sizes, int n_in,
                              void* d_out, int out_size, void* d_ws, size_t ws_size,
                              hipStream_t stream) {
    const float* emb = (const float*)d_in[0];
    const float* cent = (const float*)d_in[1];
    const int* labw = (const int*)d_in[2];
    float* out = (float*)d_out;

    const int B = in_sizes[0] / 256;
    const int K = in_sizes[1] / 256;
    const float invB = 1.0f / (float)B;

    char* ws = (char*)d_ws;
    const size_t off_c2 = 0;                     // K floats
    const size_t off_cimg = (size_t)K * 4 + 4096;
    const size_t req = off_cimg + (size_t)K * 256;   // i8 image: 256 B/centroid

    const int nchunk = K / 128;                  // chunks per column half
    if (ws_size >= req && (K % 128) == 0 && nchunk >= 3 && K <= 1024 && (B % 128) == 0) {
        const int ncb = K / 16;                  // col-blocks of 16
        const int nblk = (ncb + 3) / 4;          // image blocks
        cent_prep_kernel<<<nblk + 1, 256, 0, stream>>>(
            cent, ws + off_cimg, (float*)(ws + off_c2), out, out_size, ncb, nblk);

        hipFuncSetAttribute(reinterpret_cast<const void*>(main16_kernel),
                            hipFuncAttributeMaxDynamicSharedMemorySize, MAIN_SMEM);
        main16_kernel<<<(B / 128) * 2, 256, MAIN_SMEM, stream>>>(
            emb, ws + off_cimg, (const float*)(ws + off_c2), labw, in_sizes[2],
            out, K, nchunk, invB);
    } else {
        fb_detect_kernel<<<1, 256, 0, stream>>>((const unsigned*)d_in[2], in_sizes[2],
                                                out, out_size);
        hipFuncSetAttribute(reinterpret_cast<const void*>(fb_loss_kernel),
                            hipFuncAttributeMaxDynamicSharedMemorySize, FB_SMEM);
        fb_loss_kernel<<<B / 128, FB_THREADS, FB_SMEM, stream>>>(
            emb, cent, labw, out, K / 128, invB);
    }
}

// Round 22
// 40.189 us; speedup vs baseline: 1.2854x; 1.2854x over previous
//
#include <hip/hip_runtime.h>
#include <hip/hip_bf16.h>
#include <math.h>

typedef int   i32x4 __attribute__((ext_vector_type(4)));
typedef float f32x4 __attribute__((ext_vector_type(4)));

static __device__ __forceinline__ int pack4i8(float4 u) {
    int x0 = (int)rintf(fminf(fmaxf(u.x * 16.0f, -127.0f), 127.0f));
    int x1 = (int)rintf(fminf(fmaxf(u.y * 16.0f, -127.0f), 127.0f));
    int x2 = (int)rintf(fminf(fmaxf(u.z * 16.0f, -127.0f), 127.0f));
    int x3 = (int)rintf(fminf(fmaxf(u.w * 16.0f, -127.0f), 127.0f));
    return (x0 & 255) | ((x1 & 255) << 8) | ((x2 & 255) << 16) | ((x3 & 255) << 24);
}

static __device__ __forceinline__ void async_cp16(const void* gsrc, void* ldsdst) {
    __builtin_amdgcn_global_load_lds(
        (const __attribute__((address_space(1))) void*)gsrc,
        (__attribute__((address_space(3))) void*)ldsdst, 16, 0, 0);
}

// ---- cent_prep_i8: blocks [0,nblk): i8 image + exact fp32 c2; last: zero ----
// img[cb16][kb(0..3)][lane][j] = q16(cent[cb*16 + (lane&15)][kb*64 + (lane>>4)*16 + j])
__global__ __launch_bounds__(256) void cent_prep_kernel(
    const float* __restrict__ cent, char* __restrict__ Cimg,
    float* __restrict__ c2g, float* __restrict__ out, int out_size,
    int ncb, int nblk) {
    const int tid = threadIdx.x, lane = tid & 63, wv = tid >> 6;
    if ((int)blockIdx.x < nblk) {
        const int cb = blockIdx.x * 4 + wv;
        if (cb < ncb) {
            const int r = cb * 16 + (lane & 15);
            const int q = lane >> 4;
            const float4* C4 = (const float4*)cent;
            float s = 0.0f;
            #pragma unroll
            for (int kb = 0; kb < 4; ++kb) {
                i32x4 frag;
                #pragma unroll
                for (int j = 0; j < 4; ++j) {
                    float4 u = C4[(size_t)r * 64 + kb * 16 + q * 4 + j];
                    frag[j] = pack4i8(u);
                    s += u.x*u.x + u.y*u.y + u.z*u.z + u.w*u.w;
                }
                *(i32x4*)(Cimg + ((size_t)(cb * 4 + kb) * 64 + lane) * 16) = frag;
            }
            s += __shfl_xor(s, 16, 64);
            s += __shfl_xor(s, 32, 64);
            if (lane < 16) c2g[cb * 16 + lane] = s;
        }
    } else {
        for (int i = tid; i < out_size; i += 256) out[i] = 0.0f;
    }
}

// ---- main15 (R20, measured best 39.5us total): int8 MFMA winner. ------------
// R21 disproved the 2-block split (VGPR 156 > 128 -> no extra waves/SIMD, just
// duplicated prologue; 51.7us). This is the R20 configuration verbatim:
// 256 blocks (1/CU) x 256 thr / 4 waves, wave = 64r x 32c, q16 int8 MFMA K=64
// (2x bf16 rate), exact fp32 e2/c2, d2 = e2+c2-acc/128, pos = label-column
// select, margin screen d2<2 (quant slack ~0.3 << 1), depth-2 counted vmcnt
// fills (4/chunk -> waits 8/4/0), (256,1) to dodge the VGPR-cap spill trap.
#define CHUNK_BYTES 16384
// LDS: buf[4] @0 (64KB), c2l @65536 (4KB), det @69632 (16B), red @69648 (16B)
#define MAIN_SMEM 69664

__global__ __launch_bounds__(256, 1) void main15_kernel(
    const float* __restrict__ emb, const char* __restrict__ Cimg,
    const float* __restrict__ c2g, const int* __restrict__ labw, int lab_nelem,
    float* __restrict__ out, int K, int nchunk, float invB) {
    extern __shared__ char smem[];
    float*    c2l = (float*)(smem + 65536);
    unsigned* det = (unsigned*)(smem + 69632);
    float*    red = (float*)(smem + 69648);

    const int tid = threadIdx.x, lane = tid & 63, wid = tid >> 6;
    const int wr = wid >> 1;          // row half: 64 rows
    const int wc = wid & 1;           // col half: 32 of the 64 chunk cols
    const int brow0 = blockIdx.x * 128;
    const int l15 = lane & 15, q = lane >> 4;

#define ISSUE_FILLS(t_) do {                                                  \
        const char* s_ = Cimg + (size_t)(t_) * CHUNK_BYTES;                   \
        char* d_ = smem + (size_t)((t_) & 3) * CHUNK_BYTES;                   \
        _Pragma("unroll")                                                     \
        for (int i_ = 0; i_ < 4; ++i_)                                        \
            async_cp16(s_ + (i_ * 256 + tid) * 16, d_ + (i_ * 256 + tid) * 16); \
    } while (0)

    // fills for chunks 0 and 1 FIRST (oldest vmem ops; in-order vmcnt retire)
    ISSUE_FILLS(0);
    ISSUE_FILLS(1);
    asm volatile("" ::: "memory");

    // A: this wave's 64 rows -> i8 fragments (a[m][kb], 64 VGPR); exact e2.
    i32x4 a[4][4];
    float e2m[4];
    #pragma unroll
    for (int m = 0; m < 4; ++m) {
        const int rg = brow0 + wr * 64 + m * 16 + l15;
        const float4* E4 = (const float4*)emb + (size_t)rg * 64;
        float s = 0.0f;
        #pragma unroll
        for (int kb = 0; kb < 4; ++kb) {
            i32x4 frag;
            #pragma unroll
            for (int j = 0; j < 4; ++j) {
                float4 u = E4[kb * 16 + q * 4 + j];
                frag[j] = pack4i8(u);
                s += u.x*u.x + u.y*u.y + u.z*u.z + u.w*u.w;
            }
            a[m][kb] = frag;
        }
        s += __shfl_xor(s, 16, 64);
        s += __shfl_xor(s, 32, 64);
        e2m[m] = s;                    // exact e2 of row wr*64 + m*16 + l15
    }

    // c2 -> LDS
    for (int i = tid; i < K; i += 256) c2l[i] = c2g[i];

    // label-width detect from a small fixed window (identical in all blocks)
    {
        int npairs = lab_nelem / 2; if (npairs > 512) npairs = 512;
        unsigned accw = 0;
        const unsigned* w = (const unsigned*)labw;
        for (int i = tid; i < npairs; i += 256) accw |= w[2 * i + 1];
        #pragma unroll
        for (int d = 32; d >= 1; d >>= 1) accw |= __shfl_xor(accw, d, 64);
        if (lane == 0) det[wid] = accw;
    }
    __syncthreads();
    const int is32 = ((det[0] | det[1] | det[2] | det[3]) != 0);
    const int lab_self = is32 ? labw[brow0 + wr * 64 + lane]
                              : labw[2 * (brow0 + wr * 64 + lane)];

    // acc-row r of tile m is global row wr*64 + m*16 + q*4 + r
    float er[4][4]; int lb[4][4];
    #pragma unroll
    for (int m = 0; m < 4; ++m)
        #pragma unroll
        for (int r = 0; r < 4; ++r) {
            er[m][r] = __shfl(e2m[m], q * 4 + r, 64);
            lb[m][r] = __shfl(lab_self, m * 16 + q * 4 + r, 64);
        }

    float fsum = 0.0f;

#define CHUNK_BODY(t_)  do {                                                  \
        const char* Bbuf = smem + (size_t)((t_) & 3) * CHUNK_BYTES;           \
        const int cg0 = (t_) * 64 + wc * 32 + l15;                            \
        const float c2v0 = c2l[cg0];                                          \
        const float c2v1 = c2l[cg0 + 16];                                     \
        i32x4 acc[4][2];                                                      \
        _Pragma("unroll")                                                     \
        for (int m = 0; m < 4; ++m) {                                         \
            acc[m][0] = (i32x4){0, 0, 0, 0};                                  \
            acc[m][1] = (i32x4){0, 0, 0, 0};                                  \
        }                                                                     \
        _Pragma("unroll")                                                     \
        for (int kb = 0; kb < 4; ++kb) {                                      \
            i32x4 b0 = *(const i32x4*)(Bbuf + ((size_t)((wc * 2 + 0) * 4 + kb) * 64 + lane) * 16); \
            i32x4 b1 = *(const i32x4*)(Bbuf + ((size_t)((wc * 2 + 1) * 4 + kb) * 64 + lane) * 16); \
            _Pragma("unroll")                                                 \
            for (int m = 0; m < 4; ++m) {                                     \
                acc[m][0] = __builtin_amdgcn_mfma_i32_16x16x64_i8(a[m][kb], b0, acc[m][0], 0, 0, 0); \
                acc[m][1] = __builtin_amdgcn_mfma_i32_16x16x64_i8(a[m][kb], b1, acc[m][1], 0, 0, 0); \
            }                                                                 \
        }                                                                     \
        float mn = 3.0e38f;                                                   \
        _Pragma("unroll")                                                     \
        for (int m = 0; m < 4; ++m)                                           \
            _Pragma("unroll")                                                 \
            for (int r = 0; r < 4; ++r) {                                     \
                float d20 = fmaf(-0.0078125f, (float)acc[m][0][r], er[m][r] + c2v0); \
                float d21 = fmaf(-0.0078125f, (float)acc[m][1][r], er[m][r] + c2v1); \
                fsum += (cg0 == lb[m][r]) ? fmaxf(d20, 0.0f) : 0.0f;          \
                fsum += (cg0 + 16 == lb[m][r]) ? fmaxf(d21, 0.0f) : 0.0f;     \
                mn = fminf(mn, fminf(d20, d21));                              \
            }                                                                 \
        if (__builtin_expect(__any(mn < 2.0f), 0)) {   /* rare: margin */     \
            _Pragma("unroll")                                                 \
            for (int m = 0; m < 4; ++m)                                       \
                _Pragma("unroll")                                             \
                for (int n = 0; n < 2; ++n)                                   \
                    _Pragma("unroll")                                         \
                    for (int r = 0; r < 4; ++r) {                             \
                        float c2v = (n == 0) ? c2v0 : c2v1;                   \
                        float d2 = fmaxf(fmaf(-0.0078125f, (float)acc[m][n][r], er[m][r] + c2v), 0.0f); \
                        int cg = cg0 + n * 16;                                \
                        if (d2 < 1.0f && cg != lb[m][r]) {                    \
                            float tt = 1.0f - sqrtf(d2);                      \
                            fsum += tt * tt;                                  \
                        }                                                     \
                    }                                                         \
        }                                                                     \
    } while (0)

    // steady loop: fills(t+2) in flight, wait only for fills(t)
    int t = 0;
    for (; t < nchunk - 2; ++t) {
        __builtin_amdgcn_s_barrier();
        ISSUE_FILLS(t + 2);
        asm volatile("s_waitcnt vmcnt(8)" ::: "memory");
        CHUNK_BODY(t);
    }
    __builtin_amdgcn_s_barrier();
    asm volatile("s_waitcnt vmcnt(4)" ::: "memory");
    CHUNK_BODY(t);
    ++t;
    __builtin_amdgcn_s_barrier();
    asm volatile("s_waitcnt vmcnt(0)" ::: "memory");
    CHUNK_BODY(t);

#undef CHUNK_BODY
#undef ISSUE_FILLS

    #pragma unroll
    for (int d = 32; d >= 1; d >>= 1) fsum += __shfl_xor(fsum, d, 64);
    __syncthreads();
    if (lane == 0) red[wid] = fsum;
    __syncthreads();
    if (tid == 0)
        atomicAdd(out, (red[0] + red[1] + red[2] + red[3]) * invB);
}

// ======================= fallback (round-1, verified) ========================
#define FB_THREADS 512
#define FB_SMEM 132672
typedef short bf16x8 __attribute__((ext_vector_type(8)));
__device__ int g_lab_is64;

static __device__ __forceinline__ unsigned short f2bf(float x) {
    unsigned u = __builtin_bit_cast(unsigned, x);
    return (unsigned short)((u + 0x7fffu + ((u >> 16) & 1u)) >> 16);
}

__global__ void fb_detect_kernel(const unsigned* __restrict__ w, int nelem,
                                 float* __restrict__ out, int out_size) {
    __shared__ unsigned red[256];
    unsigned acc = 0;
    for (int i = threadIdx.x; i < nelem / 2; i += 256) acc |= w[2 * i + 1];
    red[threadIdx.x] = acc;
    __syncthreads();
    for (int s = 128; s > 0; s >>= 1) {
        if (threadIdx.x < s) red[threadIdx.x] |= red[threadIdx.x + s];
        __syncthreads();
    }
    if (threadIdx.x == 0) g_lab_is64 = (red[0] == 0u) ? 1 : 0;
    for (int i = threadIdx.x; i < out_size; i += 256) out[i] = 0.0f;
}

__global__ __launch_bounds__(FB_THREADS) void fb_loss_kernel(
    const float* __restrict__ emb, const float* __restrict__ cent,
    const int* __restrict__ labw, float* __restrict__ out,
    int nchunk, float invB) {
    extern __shared__ char smem[];
    char* Abf = smem;
    char* Cbf = smem + 65536;
    float* e2 = (float*)(smem + 131072);
    float* c2 = (float*)(smem + 131584);
    int* lab = (int*)(smem + 132096);
    float* red = (float*)(smem + 132608);

    const int tid = threadIdx.x, lane = tid & 63, wid = tid >> 6;
    const int row0 = blockIdx.x * 128;
    const int is64 = g_lab_is64;

    for (int j = 0; j < 16; ++j) {
        int f4 = tid + j * FB_THREADS;
        int r = f4 >> 6, c4 = f4 & 63;
        float4 v = ((const float4*)emb)[(size_t)(row0 + r) * 64 + c4];
        ushort4 h;
        h.x = f2bf(v.x); h.y = f2bf(v.y); h.z = f2bf(v.z); h.w = f2bf(v.w);
        int off = (c4 * 8) ^ ((r & 7) << 4);
        *(ushort4*)(Abf + r * 512 + off) = h;
        float s = v.x*v.x + v.y*v.y + v.z*v.z + v.w*v.w;
        #pragma unroll
        for (int m = 32; m >= 1; m >>= 1) s += __shfl_xor(s, m, 64);
        if (lane == 0) e2[r] = s;
    }
    if (tid < 128) {
        int b = row0 + tid;
        lab[tid] = is64 ? labw[2 * b] : labw[b];
    }
    __syncthreads();

    const int wr = wid >> 1, wc = wid & 1;
    const int l15 = lane & 15, l16 = lane >> 4;
    const int swz = (l15 & 7) << 4;

    float e2v[2][4]; int labv[2][4];
    #pragma unroll
    for (int m = 0; m < 2; ++m)
        #pragma unroll
        for (int r = 0; r < 4; ++r) {
            int rr = wr * 32 + m * 16 + l16 * 4 + r;
            e2v[m][r] = e2[rr]; labv[m][r] = lab[rr];
        }

    float fsum = 0.0f;
    for (int ch = 0; ch < nchunk; ++ch) {
        const float* cbase = cent + (size_t)ch * 128 * 256;
        for (int j = 0; j < 16; ++j) {
            int f4 = tid + j * FB_THREADS;
            int r = f4 >> 6, c4 = f4 & 63;
            float4 v = ((const float4*)cbase)[(size_t)r * 64 + c4];
            ushort4 h;
            h.x = f2bf(v.x); h.y = f2bf(v.y); h.z = f2bf(v.z); h.w = f2bf(v.w);
            int off = (c4 * 8) ^ ((r & 7) << 4);
            *(ushort4*)(Cbf + r * 512 + off) = h;
            float s = v.x*v.x + v.y*v.y + v.z*v.z + v.w*v.w;
            #pragma unroll
            for (int m = 32; m >= 1; m >>= 1) s += __shfl_xor(s, m, 64);
            if (lane == 0) c2[r] = s;
        }
        __syncthreads();

        f32x4 acc[2][4];
        #pragma unroll
        for (int m = 0; m < 2; ++m)
            #pragma unroll
            for (int n = 0; n < 4; ++n) acc[m][n] = (f32x4){0, 0, 0, 0};

        #pragma unroll
        for (int kk = 0; kk < 8; ++kk) {
            int kb = kk * 64 + l16 * 16;
            bf16x8 a[2], b[4];
            #pragma unroll
            for (int m = 0; m < 2; ++m)
                a[m] = *(const bf16x8*)(Abf + (wr * 32 + m * 16 + l15) * 512 + (kb ^ swz));
            #pragma unroll
            for (int n = 0; n < 4; ++n)
                b[n] = *(const bf16x8*)(Cbf + (wc * 64 + n * 16 + l15) * 512 + (kb ^ swz));
            #pragma unroll
            for (int m = 0; m < 2; ++m)
                #pragma unroll
                for (int n = 0; n < 4; ++n)
                    acc[m][n] = __builtin_amdgcn_mfma_f32_16x16x32_bf16(a[m], b[n], acc[m][n], 0, 0, 0);
        }

        float c2v[4]; int colg[4];
        #pragma unroll
        for (int n = 0; n < 4; ++n) {
            int cl = wc * 64 + n * 16 + l15;
            c2v[n] = c2[cl]; colg[n] = ch * 128 + cl;
        }
        unsigned need = 0;
        #pragma unroll
        for (int m = 0; m < 2; ++m)
            #pragma unroll
            for (int n = 0; n < 4; ++n)
                #pragma unroll
                for (int r = 0; r < 4; ++r) {
                    float d2 = fmaf(-2.0f, acc[m][n][r], e2v[m][r] + c2v[n]);
                    d2 = fmaxf(d2, 0.0f);
                    bool isp = (colg[n] == labv[m][r]);
                    fsum += isp ? d2 : 0.0f;
                    need |= (unsigned)((!isp) & (d2 < 1.0f)) << (m * 16 + n * 4 + r);
                }
        if (__any(need != 0)) {
            #pragma unroll
            for (int m = 0; m < 2; ++m)
                #pragma unroll
                for (int n = 0; n < 4; ++n)
                    #pragma unroll
                    for (int r = 0; r < 4; ++r)
                        if ((need >> (m * 16 + n * 4 + r)) & 1u) {
                            float d2 = fmaf(-2.0f, acc[m][n][r], e2v[m][r] + c2v[n]);
                            d2 = fmaxf(d2, 0.0f);
                            float t = 1.0f - sqrtf(d2);
                            fsum += t * t;
                        }
        }
        __syncthreads();
    }
    #pragma unroll
    for (int m = 32; m >= 1; m >>= 1) fsum += __shfl_xor(fsum, m, 64);
    if (lane == 0) red[wid] = fsum;
    __syncthreads();
    if (tid == 0) {
        float t = 0.0f;
        #pragma unroll
        for (int w = 0; w < 8; ++w) t += red[w];
        atomicAdd(out, t * invB);
    }
}

// =============================================================================
extern "C" void kernel_launch(void* const* d_in, const int* in_sizes, int n_in,
                              void* d_out, int out_size, void* d_ws, size_t ws_size,
                              hipStream_t stream) {
    const float* emb = (const float*)d_in[0];
    const float* cent = (const float*)d_in[1];
    const int* labw = (const int*)d_in[2];
    float* out = (float*)d_out;

    const int B = in_sizes[0] / 256;
    const int K = in_sizes[1] / 256;
    const float invB = 1.0f / (float)B;

    char* ws = (char*)d_ws;
    const size_t off_c2 = 0;                     // K floats
    const size_t off_cimg = (size_t)K * 4 + 4096;
    const size_t req = off_cimg + (size_t)K * 256;   // i8 image: 256 B/centroid

    const int nchunk = K / 64;
    if (ws_size >= req && (K % 64) == 0 && nchunk >= 3 && K <= 1024 && (B % 128) == 0) {
        const int ncb = K / 16;                  // col-blocks of 16
        const int nblk = (ncb + 3) / 4;          // image blocks
        cent_prep_kernel<<<nblk + 1, 256, 0, stream>>>(
            cent, ws + off_cimg, (float*)(ws + off_c2), out, out_size, ncb, nblk);

        hipFuncSetAttribute(reinterpret_cast<const void*>(main15_kernel),
                            hipFuncAttributeMaxDynamicSharedMemorySize, MAIN_SMEM);
        main15_kernel<<<B / 128, 256, MAIN_SMEM, stream>>>(
            emb, ws + off_cimg, (const float*)(ws + off_c2), labw, in_sizes[2],
            out, K, nchunk, invB);
    } else {
        fb_detect_kernel<<<1, 256, 0, stream>>>((const unsigned*)d_in[2], in_sizes[2],
                                                out, out_size);
        hipFuncSetAttribute(reinterpret_cast<const void*>(fb_loss_kernel),
                            hipFuncAttributeMaxDynamicSharedMemorySize, FB_SMEM);
        fb_loss_kernel<<<B / 128, FB_THREADS, FB_SMEM, stream>>>(
            emb, cent, labw, out, K / 128, invB);
    }
}